// Round 6
// baseline (249.898 us; speedup 1.0000x reference)
//
#include <hip/hip_runtime.h>
#include <math.h>

#define L 1024
#define SCALEF 0.125f
#define NEGF -1e30f

typedef unsigned short u16;
typedef __bf16 bf16x8 __attribute__((ext_vector_type(8)));
typedef float f32x4 __attribute__((ext_vector_type(4)));
typedef unsigned short u16x8 __attribute__((ext_vector_type(8)));
typedef unsigned short u16x4 __attribute__((ext_vector_type(4)));

#define MFMA(a, b, c) __builtin_amdgcn_mfma_f32_16x16x32_bf16(a, b, c, 0, 0, 0)

__device__ inline u16 f2b(float f) {
  union { float f; unsigned u; } v; v.f = f;
  unsigned r = v.u + 0x7fffu + ((v.u >> 16) & 1u);
  return (u16)(r >> 16);
}

// async global->LDS, 16B per lane; lds must be wave-uniform base (HW scatters lane*16)
__device__ __forceinline__ void ld16(u16* lds, const u16* g) {
  __builtin_amdgcn_global_load_lds((const __attribute__((address_space(1))) unsigned int*)g,
                                   (__attribute__((address_space(3))) unsigned int*)lds, 16, 0, 0);
}

// ---------------- prep: all fp32->bf16 casts + conv weight transposes, one launch ----------------
__global__ __launch_bounds__(256) void prep(const float* __restrict__ w, const float* __restrict__ Wqkv,
                                            const float* __restrict__ r, const float* __restrict__ Wr,
                                            const float* __restrict__ Wo,
                                            const float* __restrict__ cwq, const float* __restrict__ cwk,
                                            const float* __restrict__ cwv,
                                            u16* w_bf, u16* wqkv_bf, u16* r_bf, u16* wr_bf, u16* wo_bf,
                                            u16* wTq, u16* wTk, u16* wTv) {
  int i = blockIdx.x * 256 + threadIdx.x;
  if (i < 2621440) {
    const float* s; u16* d; int off;
    if (i < 1048576)      { s = w;    d = w_bf;    off = i; }
    else if (i < 1835008) { s = Wqkv; d = wqkv_bf; off = i - 1048576; }
    else if (i < 2097152) { s = r;    d = r_bf;    off = i - 1835008; }
    else if (i < 2359296) { s = Wr;   d = wr_bf;   off = i - 2097152; }
    else                  { s = Wo;   d = wo_bf;   off = i - 2359296; }
    float4 v = ((const float4*)s)[off];
    u16x4 o = {f2b(v.x), f2b(v.y), f2b(v.z), f2b(v.w)};
    ((u16x4*)d)[off] = o;
  } else {
    int j = i - 2621440;
    if (j < 86016) {
      int z = j / 28672, rem = j % 28672;
      const float* src = z == 0 ? cwq : z == 1 ? cwk : cwv;
      u16* dst = z == 0 ? wTq : z == 1 ? wTk : wTv;
      int tt = rem >> 12, rem2 = rem & 4095;
      int dout = rem2 >> 6, din = rem2 & 63;
      dst[rem] = f2b(src[(dout * 64 + din) * 7 + tt]);
    }
  }
}

// ---------------- R11: 256x256 8-phase GEMM (T2+T3+T4+T5), K=1024 fixed ----------------
// 512 thr = 8 waves (2M x 4N), per-wave C = 128x64. BK=32 -> 2 phases/K-tile,
// 16 MFMA + 2 global_load_lds per phase. 4-slot LDS ring (4 x 32KB): tile t in
// slot t&3; staging targets slot (t+2)&3 which is never concurrently read
// (hazard-free by construction). Counted vmcnt(4) once per K-tile, NEVER 0 in
// the main loop (T4). LDS read swizzle: physical 16B-slot = q4 ^ ((row>>1)&3),
// staged via inverse-swizzled GLOBAL source (rule #21: linear gload_lds dest).
template <int OB>
__device__ __forceinline__ void gemm256_tile(u16* lds, const u16* __restrict__ A,
                                             const u16* __restrict__ B, void* Cp,
                                             int N, int m0, int n0) {
  int t = threadIdx.x;
  int wv = t >> 6, lane = t & 63;
  int q4 = lane >> 4, li = lane & 15;
  int wm = wv >> 2, wn = wv & 3;
  int pc = (q4 ^ ((li >> 1) & 3)) << 3;              // swizzled read slot
  int cs = (((t & 3) ^ ((t >> 3) & 3)) << 3);        // inverse-swizzled source col
  const u16* Ab = A + (size_t)(m0 + (t >> 2)) * 1024 + cs;
  const u16* Bb = B + (size_t)(n0 + (t >> 2)) * 1024 + cs;
  int wo = wv * 512;
  f32x4 acc[8][4];
#pragma unroll
  for (int m = 0; m < 8; ++m)
#pragma unroll
    for (int n = 0; n < 4; ++n) acc[m][n] = (f32x4){0.f, 0.f, 0.f, 0.f};
#define STAGE_A(kt) { int sl = ((kt) & 3) * 16384, kb = (kt) * 32; \
    ld16(lds + sl + wo, Ab + kb); ld16(lds + sl + 4096 + wo, Ab + 131072 + kb); }
#define STAGE_B(kt) { int sl = ((kt) & 3) * 16384 + 8192, kb = (kt) * 32; \
    ld16(lds + sl + wo, Bb + kb); ld16(lds + sl + 4096 + wo, Bb + 131072 + kb); }
  // prologue: tiles 0 and 1 in flight; wait tile 0 (newest 4 = tile 1) -> barrier
  STAGE_A(0); STAGE_B(0); STAGE_A(1); STAGE_B(1);
  asm volatile("s_waitcnt vmcnt(4)" ::: "memory");
  __builtin_amdgcn_s_barrier();
  for (int kt = 0; kt < 32; ++kt) {
    const u16* sA = lds + (kt & 3) * 16384;
    const u16* sB = sA + 8192;
    // ---- phase A: A-rows 0..63 of wave + all B; stage A(t+2) ----
    bf16x8 fa[4], fb[4];
#pragma unroll
    for (int m = 0; m < 4; ++m) fa[m] = *(const bf16x8*)&sA[(wm * 128 + m * 16 + li) * 32 + pc];
#pragma unroll
    for (int n = 0; n < 4; ++n) fb[n] = *(const bf16x8*)&sB[(wn * 64 + n * 16 + li) * 32 + pc];
    if (kt < 30) STAGE_A(kt + 2);
    __builtin_amdgcn_s_barrier();
    __builtin_amdgcn_s_setprio(1);
#pragma unroll
    for (int m = 0; m < 4; ++m)
#pragma unroll
      for (int n = 0; n < 4; ++n) acc[m][n] = MFMA(fa[m], fb[n], acc[m][n]);
    __builtin_amdgcn_s_setprio(0);
    __builtin_amdgcn_s_barrier();
    // ---- phase B: A-rows 64..127; stage B(t+2); counted vmcnt (tile t+1 landed) ----
    bf16x8 fa2[4];
#pragma unroll
    for (int m = 0; m < 4; ++m) fa2[m] = *(const bf16x8*)&sA[(wm * 128 + 64 + m * 16 + li) * 32 + pc];
    if (kt < 30) {
      STAGE_B(kt + 2);
      asm volatile("s_waitcnt vmcnt(4)" ::: "memory");
    } else {
      asm volatile("s_waitcnt vmcnt(0)" ::: "memory");
    }
    __builtin_amdgcn_s_barrier();
    __builtin_amdgcn_s_setprio(1);
#pragma unroll
    for (int m = 0; m < 4; ++m)
#pragma unroll
      for (int n = 0; n < 4; ++n) acc[4 + m][n] = MFMA(fa2[m], fb[n], acc[4 + m][n]);
    __builtin_amdgcn_s_setprio(0);
    __builtin_amdgcn_s_barrier();
  }
#undef STAGE_A
#undef STAGE_B
#pragma unroll
  for (int m = 0; m < 8; ++m)
#pragma unroll
    for (int r = 0; r < 4; ++r) {
      size_t row = m0 + wm * 128 + m * 16 + q4 * 4 + r;
      if (OB) {
        u16* C = (u16*)Cp;
#pragma unroll
        for (int n = 0; n < 4; ++n) C[row * N + n0 + wn * 64 + n * 16 + li] = f2b(acc[m][n][r]);
      } else {
        float* C = (float*)Cp;
#pragma unroll
        for (int n = 0; n < 4; ++n) C[row * N + n0 + wn * 64 + n * 16 + li] = acc[m][n][r];
      }
    }
}

// fused QKV (192 blocks, 16x12) + r (16 blocks, 4x4) GEMM on the 256^2 8-phase tile.
// R14: XCD-aware chunked swizzle on the 192 QKV blocks (neutral at this grid
// size — kept, harmless). r blocks untouched.
__global__ __launch_bounds__(512, 1) void gemm_stage1(const u16* __restrict__ w_bf,
                                                      const u16* __restrict__ wqkv_bf,
                                                      u16* __restrict__ heads,
                                                      const u16* __restrict__ r_bf,
                                                      const u16* __restrict__ wr_bf,
                                                      u16* __restrict__ rhk) {
  __shared__ u16 lds[65536];  // 128 KB: 4 slots x (A 16KB + B 16KB)
  int id = blockIdx.x;
  if (id < 192) {
    int sid = (id & 7) * 24 + (id >> 3);  // XCD-chunked remap (bijective on [0,192))
    gemm256_tile<1>(lds, w_bf, wqkv_bf, heads, 3072, (sid / 12) << 8, (sid % 12) << 8);
  } else {
    int j = id - 192;
    gemm256_tile<1>(lds, r_bf, wr_bf, rhk, 1024, (j >> 2) << 8, (j & 3) << 8);
  }
}

// ---------------- 64x128 MFMA GEMM (double-buffered) for W_o, fp32 out ----------------
// (kept on the 2-phase 128-class tile: 256^2 would give only 64 blocks -> CU under-fill)
__global__ __launch_bounds__(256) void gemm_wo(const u16* __restrict__ A, const u16* __restrict__ B,
                                               float* __restrict__ C) {
  __shared__ u16 sA[2 * 64 * 32];
  __shared__ u16 sB[2 * 128 * 32];
  int t = threadIdx.x;
  int w = t >> 6, lane = t & 63;
  int q4 = lane >> 4, li = lane & 15;
  int m0 = blockIdx.y << 6, n0 = blockIdx.x << 7;
  int nw = w << 5;
  const int N = 1024, K = 1024;
  f32x4 acc[4][2];
#pragma unroll
  for (int i = 0; i < 4; ++i)
#pragma unroll
    for (int j = 0; j < 2; ++j) acc[i][j] = (f32x4){0.f, 0.f, 0.f, 0.f};
  int r0 = t >> 2, c0 = (t & 3) << 3;
  const u16* Ap = A + (size_t)(m0 + r0) * K + c0;
  const u16* Bp0 = B + (size_t)(n0 + r0) * K + c0;
  const u16* Bp1 = B + (size_t)(n0 + 64 + r0) * K + c0;
  int wo512 = w * 512;
  ld16(sA + wo512, Ap);
  ld16(sB + wo512, Bp0);
  ld16(sB + wo512 + 2048, Bp1);
  int cur = 0;
  for (int kb = 0; kb < K; kb += 32) {
    __syncthreads();
    int nxt = cur ^ 1;
    if (kb + 32 < K) {
      u16* nA = sA + nxt * 2048;
      u16* nB = sB + nxt * 4096;
      ld16(nA + wo512, Ap + kb + 32);
      ld16(nB + wo512, Bp0 + kb + 32);
      ld16(nB + wo512 + 2048, Bp1 + kb + 32);
    }
    const u16* cA = sA + cur * 2048;
    const u16* cB = sB + cur * 4096;
    bf16x8 fa[4], fb[2];
#pragma unroll
    for (int i = 0; i < 4; ++i) fa[i] = *(const bf16x8*)&cA[(i * 16 + li) * 32 + q4 * 8];
#pragma unroll
    for (int j = 0; j < 2; ++j) fb[j] = *(const bf16x8*)&cB[(nw + j * 16 + li) * 32 + q4 * 8];
#pragma unroll
    for (int mt = 0; mt < 4; ++mt)
#pragma unroll
      for (int nt = 0; nt < 2; ++nt) acc[mt][nt] = MFMA(fa[mt], fb[nt], acc[mt][nt]);
    cur = nxt;
  }
#pragma unroll
  for (int mt = 0; mt < 4; ++mt)
#pragma unroll
    for (int r = 0; r < 4; ++r) {
      size_t row = m0 + mt * 16 + q4 * 4 + r;
#pragma unroll
      for (int nt = 0; nt < 2; ++nt) C[row * N + n0 + nw + nt * 16 + li] = acc[mt][nt][r];
    }
}

// ---------------- conv1d k=7 via MFMA; z=0:q, 1:k, 2:v (v written transposed [bn][d][L]) ----------------
// (R8 form — do NOT fuse foreign GEMM work in here; R9 tried and regressed.)
__global__ __launch_bounds__(256) void conv3(const u16* __restrict__ x,
                                             const u16* __restrict__ wTq, const u16* __restrict__ wTk,
                                             const u16* __restrict__ wTv,
                                             const float* __restrict__ cbq, const float* __restrict__ cbk,
                                             const float* __restrict__ cbv,
                                             u16* __restrict__ qh, u16* __restrict__ kh, u16* __restrict__ vtg) {
  __shared__ u16 sX[70 * 72];
  int z = blockIdx.z;
  const u16* wT = z == 0 ? wTq : z == 1 ? wTk : wTv;
  const float* bias = z == 0 ? cbq : z == 1 ? cbk : cbv;
  int t = threadIdx.x;
  int w = t >> 6, lane = t & 63;
  int q4 = lane >> 4, li = lane & 15;
  int l0 = blockIdx.x << 6, bn = blockIdx.y;
  int b = bn >> 4, n = bn & 15;
  const u16* xb = x + b * 3072 + z * 1024 + n * 64;
  for (int e = t; e < 560; e += 256) {
    int ro = e >> 3, c = e & 7;
    int l = l0 - 3 + ro;
    u16x8 v = {0, 0, 0, 0, 0, 0, 0, 0};
    if (l >= 0 && l < L) v = *(const u16x8*)(xb + (size_t)l * 12288 + c * 8);
    *(u16x8*)&sX[ro * 72 + c * 8] = v;
  }
  bf16x8 Bw[7][2];
#pragma unroll
  for (int tt = 0; tt < 7; ++tt)
#pragma unroll
    for (int kc = 0; kc < 2; ++kc)
      Bw[tt][kc] = *(const bf16x8*)(wT + (tt * 64 + w * 16 + li) * 64 + kc * 32 + q4 * 8);
  f32x4 acc[4];
#pragma unroll
  for (int i = 0; i < 4; ++i) acc[i] = (f32x4){0.f, 0.f, 0.f, 0.f};
  __syncthreads();
#pragma unroll
  for (int tt = 0; tt < 7; ++tt)
#pragma unroll
    for (int kc = 0; kc < 2; ++kc)
#pragma unroll
      for (int mt = 0; mt < 4; ++mt) {
        bf16x8 a = *(const bf16x8*)&sX[(mt * 16 + li + tt) * 72 + kc * 32 + q4 * 8];
        acc[mt] = MFMA(a, Bw[tt][kc], acc[mt]);
      }
  float bv = bias[w * 16 + li];
  if (z < 2) {
    u16* out = z == 0 ? qh : kh;
#pragma unroll
    for (int mt = 0; mt < 4; ++mt)
#pragma unroll
      for (int r = 0; r < 4; ++r) {
        int l = l0 + mt * 16 + q4 * 4 + r;
        out[(((size_t)l * 4 + b) * 16 + n) * 64 + w * 16 + li] = f2b(acc[mt][r] + bv);
      }
  } else {
    __syncthreads();
#pragma unroll
    for (int mt = 0; mt < 4; ++mt)
#pragma unroll
      for (int r = 0; r < 4; ++r)
        sX[(w * 16 + li) * 72 + mt * 16 + q4 * 4 + r] = f2b(acc[mt][r] + bv);
    __syncthreads();
    int d = t >> 2, ch = t & 3;
    u16x8 v0 = *(u16x8*)&sX[d * 72 + ch * 16];
    u16x8 v1 = *(u16x8*)&sX[d * 72 + ch * 16 + 8];
    u16* dst = vtg + ((size_t)bn * 64 + d) * 1024 + l0 + ch * 16;
    *(u16x8*)dst = v0;
    *(u16x8*)(dst + 8) = v1;
  }
}

// ---------------- MFMA flash attention with relative shift ----------------
// R6 structure (79us) + R8 fixed-max softmax. 512 blocks, paired q-tiles p/15-p,
// uniform 17 j-tiles, register prefetch (REQUIRED for healthy VGPR allocation).
// R7 un-pairing regressed (110us). DO NOT restructure the pairing.
// R10: sP XOR-swizzle; 1-shfl rel-shift merge; ones-MFMA row-sum (accL);
// setprio around MFMAs. (51.9 -> 46us; VGPR 120, LDS 46080, 3 blocks/CU)
// R12 FAILED (83us): sK/sR dbuf -> LDS 64.5KB -> 2 blocks/CU occupancy cliff.
// R13 FAILED (204us): launch_bounds(256,4) + V-in-reg -> VGPR spills to scratch.
// LOCAL-OPTIMUM BUDGET: LDS 46080, VGPR 120. DO NOT perturb either budget.
// R15: sliding-window sR ring. gB slides +64/jtile, so half of each 128-row
// restage was redundant. phys(l,jt) = (l + 64*jt) mod 128: overlap rows carry
// over in place; jt>=1 stages only the 64 NEW rows (pR 4->2 loads+writes).
// Reads add ((jt&1)<<6 + l) & 127. Same hazard discipline as sK (writes after
// barrier follow prior iter's reads). LDS/VGPR budgets unchanged.
__global__ __launch_bounds__(256) void rel_attn(const u16* __restrict__ qh, const u16* __restrict__ kh,
                                                const u16* __restrict__ vt, const u16* __restrict__ rhk,
                                                const float* __restrict__ rwb_, const float* __restrict__ rrb_,
                                                u16* __restrict__ vec) {
  __shared__ u16 sK[64][72];
  __shared__ u16 sVt[64][72];
  __shared__ u16 sR[128][72];
  __shared__ u16 sP[4][16][72];
  int t = threadIdx.x;
  int w = t >> 6, lane = t & 63;
  int q4 = lane >> 4, li = lane & 15;
  int p = blockIdx.x, bn = blockIdx.y;
  int b = bn >> 4, n = bn & 15;
  int base_w = 48 - w * 16;
  const u16* vtb = vt + (size_t)bn * 64 * 1024;
  int er0 = t >> 3, ec = (t & 7) * 8;
  bf16x8 vone;
#pragma unroll
  for (int j = 0; j < 8; ++j) vone[j] = (__bf16)1.0f;
  float rwbv[2][8], rrbv[2][8];
#pragma unroll
  for (int kc = 0; kc < 2; ++kc)
#pragma unroll
    for (int j = 0; j < 8; ++j) {
      int d = kc * 32 + q4 * 8 + j;
      rwbv[kc][j] = rwb_[n * 64 + d];
      rrbv[kc][j] = rrb_[n * 64 + d];
    }
  for (int half = 0; half < 2; ++half) {
    int qt = (half == 0) ? p : 15 - p;
    int i0 = qt << 6;
    bf16x8 Aw[2], Ar[2];
    {
      const u16* qrow = qh + (((size_t)(i0 + w * 16 + li) * 4 + b) * 16 + n) * 64;
#pragma unroll
      for (int kc = 0; kc < 2; ++kc) {
        bf16x8 qv = *(const bf16x8*)(qrow + kc * 32 + q4 * 8);
        bf16x8 aw, ar;
#pragma unroll
        for (int j = 0; j < 8; ++j) {
          float qf = (float)qv[j];
          aw[j] = (__bf16)(qf + rwbv[kc][j]);
          ar[j] = (__bf16)(qf + rrbv[kc][j]);
        }
        Aw[kc] = aw;
        Ar[kc] = ar;
      }
    }
    f32x4 accO[4];
#pragma unroll
    for (int i = 0; i < 4; ++i) accO[i] = (f32x4){0.f, 0.f, 0.f, 0.f};
    f32x4 accL = (f32x4){0.f, 0.f, 0.f, 0.f};  // ones-MFMA row-sum of P
    int ntile = qt + 1;
    u16x8 pK[2], pV[2], pR[4];
    {
      int j0 = 0, gB = 960 - i0;
#pragma unroll
      for (int i = 0; i < 2; ++i) {
        int row = er0 + i * 32;
        pK[i] = *(const u16x8*)(kh + (((size_t)(j0 + row) * 4 + b) * 16 + n) * 64 + ec);
        pV[i] = *(const u16x8*)(vtb + (size_t)row * 1024 + j0 + ec);
      }
#pragma unroll
      for (int i = 0; i < 4; ++i) {
        int m = er0 + i * 32;
        int g = gB + m;
        if (g > L - 1) g = L - 1;
        pR[i] = *(const u16x8*)(rhk + (size_t)g * 1024 + n * 64 + ec);
      }
    }
    for (int jt = 0; jt < ntile; ++jt) {
      int rsh = (jt & 1) << 6;  // R ring phase: phys = (logical + rsh) & 127
      __syncthreads();
#pragma unroll
      for (int i = 0; i < 2; ++i) {
        *(u16x8*)&sK[er0 + i * 32][ec] = pK[i];
        *(u16x8*)&sVt[er0 + i * 32][ec] = pV[i];
      }
      if (jt == 0) {
        // full window restage (start of each half)
#pragma unroll
        for (int i = 0; i < 4; ++i) *(u16x8*)&sR[er0 + i * 32][ec] = pR[i];
      } else {
        // only the 64 NEW rows: logical [64,128) -> phys (er0+i*32) + (rsh^64)
#pragma unroll
        for (int i = 0; i < 2; ++i) *(u16x8*)&sR[(er0 + i * 32) + (rsh ^ 64)][ec] = pR[i];
      }
      __syncthreads();
      if (jt + 1 < ntile) {
        int j0n = (jt + 1) << 6;
#pragma unroll
        for (int i = 0; i < 2; ++i) {
          int row = er0 + i * 32;
          pK[i] = *(const u16x8*)(kh + (((size_t)(j0n + row) * 4 + b) * 16 + n) * 64 + ec);
          pV[i] = *(const u16x8*)(vtb + (size_t)row * 1024 + j0n + ec);
        }
        // prefetch only window jt+1's NEW rows: logical [64,128) -> g = gB(jt+1)+64+x
        int gN = 960 - i0 + j0n + 64;
#pragma unroll
        for (int i = 0; i < 2; ++i) {
          int g = gN + er0 + i * 32;
          if (g > L - 1) g = L - 1;
          pR[i] = *(const u16x8*)(rhk + (size_t)g * 1024 + n * 64 + ec);
        }
      }
      int j0 = jt << 6;
      f32x4 accS[4], accG[5];
#pragma unroll
      for (int i = 0; i < 4; ++i) accS[i] = (f32x4){0.f, 0.f, 0.f, 0.f};
#pragma unroll
      for (int i = 0; i < 5; ++i) accG[i] = (f32x4){0.f, 0.f, 0.f, 0.f};
      __builtin_amdgcn_s_setprio(1);
#pragma unroll
      for (int kc = 0; kc < 2; ++kc) {
#pragma unroll
        for (int nt = 0; nt < 4; ++nt) {
          bf16x8 fk = *(const bf16x8*)&sK[nt * 16 + li][kc * 32 + q4 * 8];
          accS[nt] = MFMA(Aw[kc], fk, accS[nt]);
        }
#pragma unroll
        for (int nt = 0; nt < 5; ++nt) {
          int rrow = (base_w + nt * 16 + li + rsh) & 127;
          bf16x8 fr = *(const bf16x8*)&sR[rrow][kc * 32 + q4 * 8];
          accG[nt] = MFMA(Ar[kc], fr, accG[nt]);
        }
      }
      __builtin_amdgcn_s_setprio(0);
      // rel-shift merge: pre-merge the two candidate G tiles on the SOURCE lane
      // (src/dst share q4 hence il), then a single bpermute moves it.
      float Sv[4][4];
#pragma unroll
      for (int nt = 0; nt < 4; ++nt)
#pragma unroll
        for (int r = 0; r < 4; ++r) {
          int il = q4 * 4 + r;
          int srcc = li + 15 - il;
          int lsrc = (lane & 48) | (srcc & 15);
          float pm = (li >= 15 - il) ? accG[nt][r] : accG[nt + 1][r];
          float g = __shfl(pm, lsrc);
          Sv[nt][r] = (accS[nt][r] + g) * SCALEF;
        }
      if (jt == qt) {
#pragma unroll
        for (int nt = 0; nt < 4; ++nt)
#pragma unroll
          for (int r = 0; r < 4; ++r)
            if (j0 + nt * 16 + li > i0 + w * 16 + q4 * 4 + r) Sv[nt][r] = NEGF;
      }
      // exp + swizzled P store (row = q4*4+r; col bits[3:4] ^= q4 -> conflict-free)
#pragma unroll
      for (int nt = 0; nt < 4; ++nt)
#pragma unroll
        for (int r = 0; r < 4; ++r) {
          float pv = __expf(Sv[nt][r]);
          sP[w][q4 * 4 + r][(nt * 16 + li) ^ (q4 << 3)] = f2b(pv);
        }
      __builtin_amdgcn_s_setprio(1);
#pragma unroll
      for (int kc = 0; kc < 2; ++kc) {
        bf16x8 ap = *(const bf16x8*)&sP[w][li][kc * 32 + ((q4 ^ ((li >> 2) & 3)) << 3)];
        accL = MFMA(ap, vone, accL);  // row-sum of P: replaces the psum butterfly
#pragma unroll
        for (int nt = 0; nt < 4; ++nt) {
          bf16x8 fv = *(const bf16x8*)&sVt[nt * 16 + li][kc * 32 + q4 * 8];
          accO[nt] = MFMA(ap, fv, accO[nt]);
        }
      }
      __builtin_amdgcn_s_setprio(0);
    }
#pragma unroll
    for (int r = 0; r < 4; ++r) {
      int il = q4 * 4 + r;
      int ig = i0 + w * 16 + il;
      float inv = 1.0f / accL[r];
      u16* orow = vec + (((size_t)ig * 4 + b) * 16 + n) * 64;
#pragma unroll
      for (int nt = 0; nt < 4; ++nt) orow[nt * 16 + li] = f2b(accO[nt][r] * inv);
    }
  }
}

// ---------------- residual + layernorm ----------------
__global__ __launch_bounds__(256) void resid_ln(const float* __restrict__ w,
                                                const float* __restrict__ attn,
                                                const float* __restrict__ gamma,
                                                const float* __restrict__ beta,
                                                float* __restrict__ out) {
  __shared__ float ssum[4], ssq[4];
  int row = blockIdx.x, t = threadIdx.x;
  float4 xw = *(const float4*)&w[(size_t)row * 1024 + t * 4];
  float4 xa = *(const float4*)&attn[(size_t)row * 1024 + t * 4];
  float4 x = make_float4(xw.x + xa.x, xw.y + xa.y, xw.z + xa.z, xw.w + xa.w);
  float s = x.x + x.y + x.z + x.w;
  float sq = x.x * x.x + x.y * x.y + x.z * x.z + x.w * x.w;
#pragma unroll
  for (int off = 32; off > 0; off >>= 1) {
    s += __shfl_down(s, off);
    sq += __shfl_down(sq, off);
  }
  int wid = t >> 6;
  if ((t & 63) == 0) { ssum[wid] = s; ssq[wid] = sq; }
  __syncthreads();
  s = ssum[0] + ssum[1] + ssum[2] + ssum[3];
  sq = ssq[0] + ssq[1] + ssq[2] + ssq[3];
  float mean = s * (1.0f / 1024.0f);
  float var = sq * (1.0f / 1024.0f) - mean * mean;
  float rstd = rsqrtf(var + 1e-5f);
  float4 g = *(const float4*)&gamma[t * 4];
  float4 bb = *(const float4*)&beta[t * 4];
  float4 o;
  o.x = (x.x - mean) * rstd * g.x + bb.x;
  o.y = (x.y - mean) * rstd * g.y + bb.y;
  o.z = (x.z - mean) * rstd * g.z + bb.z;
  o.w = (x.w - mean) * rstd * g.w + bb.w;
  *(float4*)&out[(size_t)row * 1024 + t * 4] = o;
}

extern "C" void kernel_launch(void* const* d_in, const int* in_sizes, int n_in,
                              void* d_out, int out_size, void* d_ws, size_t ws_size,
                              hipStream_t stream) {
  const float* w     = (const float*)d_in[0];
  const float* r     = (const float*)d_in[1];
  const float* rwb   = (const float*)d_in[2];
  const float* rrb   = (const float*)d_in[3];
  const float* W_qkv = (const float*)d_in[4];
  const float* W_r   = (const float*)d_in[5];
  const float* W_o   = (const float*)d_in[6];
  const float* cwq   = (const float*)d_in[7];
  const float* cbq   = (const float*)d_in[8];
  const float* cwk   = (const float*)d_in[9];
  const float* cbk   = (const float*)d_in[10];
  const float* cwv   = (const float*)d_in[11];
  const float* cbv   = (const float*)d_in[12];
  const float* gamma = (const float*)d_in[13];
  const float* beta  = (const float*)d_in[14];
  float* outp = (float*)d_out;

  char* wsb = (char*)d_ws;
  u16*   heads   = (u16*)(wsb);                 // [4096][3072] bf16 = 24 MB
  u16*   vec     = (u16*)(wsb);                 // alias (heads dead after convs): 8 MB
  float* attnf   = (float*)(wsb + 8388608);     // 16 MB (within dead heads region)
  u16*   qh      = (u16*)(wsb + 25165824);      // 8 MB
  u16*   kh      = (u16*)(wsb + 33554432);      // 8 MB
  u16*   rhk     = (u16*)(wsb + 50331648);      // 2 MB
  u16*   w_bf    = (u16*)(wsb + 52428800);
  u16*   wqkv_bf = (u16*)(wsb + 60817408);
  u16*   r_bf    = (u16*)(wsb + 67108864);
  u16*   wr_bf   = (u16*)(wsb + 69206016);
  u16*   wo_bf   = (u16*)(wsb + 71303168);
  u16*   wTq     = (u16*)(wsb + 73400320);
  u16*   wTk     = (u16*)(wsb + 73457664);
  u16*   wTv     = (u16*)(wsb + 73515008);
  u16*   vt      = (u16*)(wsb + 73572352);      // [64][64][1024] bf16 = 8 MB

  dim3 blk(256);
  prep<<<10576, blk, 0, stream>>>(w, W_qkv, r, W_r, W_o, cwq, cwk, cwv,
                                  w_bf, wqkv_bf, r_bf, wr_bf, wo_bf, wTq, wTk, wTv);
  gemm_stage1<<<208, dim3(512), 0, stream>>>(w_bf, wqkv_bf, heads, r_bf, wr_bf, rhk);
  conv3<<<dim3(16, 64, 3), blk, 0, stream>>>(heads, wTq, wTk, wTv, cbq, cbk, cbv, qh, kh, vt);
  rel_attn<<<dim3(8, 64), blk, 0, stream>>>(qh, kh, vt, rhk, rwb, rrb, vec);
  gemm_wo<<<dim3(8, 64), blk, 0, stream>>>(vec, wo_bf, attnf);
  resid_ln<<<4096, blk, 0, stream>>>(w, attnf, gamma, beta, outp);
}

// Round 7
// 248.745 us; speedup vs baseline: 1.0046x; 1.0046x over previous
//
#include <hip/hip_runtime.h>
#include <math.h>

#define L 1024
#define SCALEF 0.125f
#define NEGF -1e30f

typedef unsigned short u16;
typedef __bf16 bf16x8 __attribute__((ext_vector_type(8)));
typedef float f32x4 __attribute__((ext_vector_type(4)));
typedef unsigned short u16x8 __attribute__((ext_vector_type(8)));
typedef unsigned short u16x4 __attribute__((ext_vector_type(4)));

#define MFMA(a, b, c) __builtin_amdgcn_mfma_f32_16x16x32_bf16(a, b, c, 0, 0, 0)

// R16: native RNE cast (bit-identical to the old bit-twiddle RNE) — compiler
// fuses adjacent pairs into v_cvt_pk_bf16_f32 (2 converts/op vs ~4 ops each).
__device__ inline u16 f2b(float f) {
  __bf16 h = (__bf16)f;
  union { __bf16 h; u16 u; } v; v.h = h;
  return v.u;
}

// async global->LDS, 16B per lane; lds must be wave-uniform base (HW scatters lane*16)
__device__ __forceinline__ void ld16(u16* lds, const u16* g) {
  __builtin_amdgcn_global_load_lds((const __attribute__((address_space(1))) unsigned int*)g,
                                   (__attribute__((address_space(3))) unsigned int*)lds, 16, 0, 0);
}

// ---------------- prep: all fp32->bf16 casts + conv weight transposes, one launch ----------------
__global__ __launch_bounds__(256) void prep(const float* __restrict__ w, const float* __restrict__ Wqkv,
                                            const float* __restrict__ r, const float* __restrict__ Wr,
                                            const float* __restrict__ Wo,
                                            const float* __restrict__ cwq, const float* __restrict__ cwk,
                                            const float* __restrict__ cwv,
                                            u16* w_bf, u16* wqkv_bf, u16* r_bf, u16* wr_bf, u16* wo_bf,
                                            u16* wTq, u16* wTk, u16* wTv) {
  int i = blockIdx.x * 256 + threadIdx.x;
  if (i < 2621440) {
    const float* s; u16* d; int off;
    if (i < 1048576)      { s = w;    d = w_bf;    off = i; }
    else if (i < 1835008) { s = Wqkv; d = wqkv_bf; off = i - 1048576; }
    else if (i < 2097152) { s = r;    d = r_bf;    off = i - 1835008; }
    else if (i < 2359296) { s = Wr;   d = wr_bf;   off = i - 2097152; }
    else                  { s = Wo;   d = wo_bf;   off = i - 2359296; }
    float4 v = ((const float4*)s)[off];
    u16x4 o = {f2b(v.x), f2b(v.y), f2b(v.z), f2b(v.w)};
    ((u16x4*)d)[off] = o;
  } else {
    int j = i - 2621440;
    if (j < 86016) {
      int z = j / 28672, rem = j % 28672;
      const float* src = z == 0 ? cwq : z == 1 ? cwk : cwv;
      u16* dst = z == 0 ? wTq : z == 1 ? wTk : wTv;
      int tt = rem >> 12, rem2 = rem & 4095;
      int dout = rem2 >> 6, din = rem2 & 63;
      dst[rem] = f2b(src[(dout * 64 + din) * 7 + tt]);
    }
  }
}

// ---------------- R11: 256x256 8-phase GEMM (T2+T3+T4+T5), K=1024 fixed ----------------
// 512 thr = 8 waves (2M x 4N), per-wave C = 128x64. BK=32 -> 2 phases/K-tile,
// 16 MFMA + 2 global_load_lds per phase. 4-slot LDS ring (4 x 32KB): tile t in
// slot t&3; staging targets slot (t+2)&3 which is never concurrently read
// (hazard-free by construction). Counted vmcnt(4) once per K-tile, NEVER 0 in
// the main loop (T4). LDS read swizzle: physical 16B-slot = q4 ^ ((row>>1)&3),
// staged via inverse-swizzled GLOBAL source (rule #21: linear gload_lds dest).
template <int OB>
__device__ __forceinline__ void gemm256_tile(u16* lds, const u16* __restrict__ A,
                                             const u16* __restrict__ B, void* Cp,
                                             int N, int m0, int n0) {
  int t = threadIdx.x;
  int wv = t >> 6, lane = t & 63;
  int q4 = lane >> 4, li = lane & 15;
  int wm = wv >> 2, wn = wv & 3;
  int pc = (q4 ^ ((li >> 1) & 3)) << 3;              // swizzled read slot
  int cs = (((t & 3) ^ ((t >> 3) & 3)) << 3);        // inverse-swizzled source col
  const u16* Ab = A + (size_t)(m0 + (t >> 2)) * 1024 + cs;
  const u16* Bb = B + (size_t)(n0 + (t >> 2)) * 1024 + cs;
  int wo = wv * 512;
  f32x4 acc[8][4];
#pragma unroll
  for (int m = 0; m < 8; ++m)
#pragma unroll
    for (int n = 0; n < 4; ++n) acc[m][n] = (f32x4){0.f, 0.f, 0.f, 0.f};
#define STAGE_A(kt) { int sl = ((kt) & 3) * 16384, kb = (kt) * 32; \
    ld16(lds + sl + wo, Ab + kb); ld16(lds + sl + 4096 + wo, Ab + 131072 + kb); }
#define STAGE_B(kt) { int sl = ((kt) & 3) * 16384 + 8192, kb = (kt) * 32; \
    ld16(lds + sl + wo, Bb + kb); ld16(lds + sl + 4096 + wo, Bb + 131072 + kb); }
  // prologue: tiles 0 and 1 in flight; wait tile 0 (newest 4 = tile 1) -> barrier
  STAGE_A(0); STAGE_B(0); STAGE_A(1); STAGE_B(1);
  asm volatile("s_waitcnt vmcnt(4)" ::: "memory");
  __builtin_amdgcn_s_barrier();
  for (int kt = 0; kt < 32; ++kt) {
    const u16* sA = lds + (kt & 3) * 16384;
    const u16* sB = sA + 8192;
    // ---- phase A: A-rows 0..63 of wave + all B; stage A(t+2) ----
    bf16x8 fa[4], fb[4];
#pragma unroll
    for (int m = 0; m < 4; ++m) fa[m] = *(const bf16x8*)&sA[(wm * 128 + m * 16 + li) * 32 + pc];
#pragma unroll
    for (int n = 0; n < 4; ++n) fb[n] = *(const bf16x8*)&sB[(wn * 64 + n * 16 + li) * 32 + pc];
    if (kt < 30) STAGE_A(kt + 2);
    __builtin_amdgcn_s_barrier();
    __builtin_amdgcn_s_setprio(1);
#pragma unroll
    for (int m = 0; m < 4; ++m)
#pragma unroll
      for (int n = 0; n < 4; ++n) acc[m][n] = MFMA(fa[m], fb[n], acc[m][n]);
    __builtin_amdgcn_s_setprio(0);
    __builtin_amdgcn_s_barrier();
    // ---- phase B: A-rows 64..127; stage B(t+2); counted vmcnt (tile t+1 landed) ----
    bf16x8 fa2[4];
#pragma unroll
    for (int m = 0; m < 4; ++m) fa2[m] = *(const bf16x8*)&sA[(wm * 128 + 64 + m * 16 + li) * 32 + pc];
    if (kt < 30) {
      STAGE_B(kt + 2);
      asm volatile("s_waitcnt vmcnt(4)" ::: "memory");
    } else {
      asm volatile("s_waitcnt vmcnt(0)" ::: "memory");
    }
    __builtin_amdgcn_s_barrier();
    __builtin_amdgcn_s_setprio(1);
#pragma unroll
    for (int m = 0; m < 4; ++m)
#pragma unroll
      for (int n = 0; n < 4; ++n) acc[4 + m][n] = MFMA(fa2[m], fb[n], acc[4 + m][n]);
    __builtin_amdgcn_s_setprio(0);
    __builtin_amdgcn_s_barrier();
  }
#undef STAGE_A
#undef STAGE_B
#pragma unroll
  for (int m = 0; m < 8; ++m)
#pragma unroll
    for (int r = 0; r < 4; ++r) {
      size_t row = m0 + wm * 128 + m * 16 + q4 * 4 + r;
      if (OB) {
        u16* C = (u16*)Cp;
#pragma unroll
        for (int n = 0; n < 4; ++n) C[row * N + n0 + wn * 64 + n * 16 + li] = f2b(acc[m][n][r]);
      } else {
        float* C = (float*)Cp;
#pragma unroll
        for (int n = 0; n < 4; ++n) C[row * N + n0 + wn * 64 + n * 16 + li] = acc[m][n][r];
      }
    }
}

// fused QKV (192 blocks, 16x12) + r (16 blocks, 4x4) GEMM on the 256^2 8-phase tile.
// R14: XCD-aware chunked swizzle on the 192 QKV blocks (neutral at this grid
// size — kept, harmless). r blocks untouched.
__global__ __launch_bounds__(512, 1) void gemm_stage1(const u16* __restrict__ w_bf,
                                                      const u16* __restrict__ wqkv_bf,
                                                      u16* __restrict__ heads,
                                                      const u16* __restrict__ r_bf,
                                                      const u16* __restrict__ wr_bf,
                                                      u16* __restrict__ rhk) {
  __shared__ u16 lds[65536];  // 128 KB: 4 slots x (A 16KB + B 16KB)
  int id = blockIdx.x;
  if (id < 192) {
    int sid = (id & 7) * 24 + (id >> 3);  // XCD-chunked remap (bijective on [0,192))
    gemm256_tile<1>(lds, w_bf, wqkv_bf, heads, 3072, (sid / 12) << 8, (sid % 12) << 8);
  } else {
    int j = id - 192;
    gemm256_tile<1>(lds, r_bf, wr_bf, rhk, 1024, (j >> 2) << 8, (j & 3) << 8);
  }
}

// ---------------- 64x128 MFMA GEMM (double-buffered) for W_o, fp32 out ----------------
// (kept on the 2-phase 128-class tile: 256^2 would give only 64 blocks -> CU under-fill)
__global__ __launch_bounds__(256) void gemm_wo(const u16* __restrict__ A, const u16* __restrict__ B,
                                               float* __restrict__ C) {
  __shared__ u16 sA[2 * 64 * 32];
  __shared__ u16 sB[2 * 128 * 32];
  int t = threadIdx.x;
  int w = t >> 6, lane = t & 63;
  int q4 = lane >> 4, li = lane & 15;
  int m0 = blockIdx.y << 6, n0 = blockIdx.x << 7;
  int nw = w << 5;
  const int N = 1024, K = 1024;
  f32x4 acc[4][2];
#pragma unroll
  for (int i = 0; i < 4; ++i)
#pragma unroll
    for (int j = 0; j < 2; ++j) acc[i][j] = (f32x4){0.f, 0.f, 0.f, 0.f};
  int r0 = t >> 2, c0 = (t & 3) << 3;
  const u16* Ap = A + (size_t)(m0 + r0) * K + c0;
  const u16* Bp0 = B + (size_t)(n0 + r0) * K + c0;
  const u16* Bp1 = B + (size_t)(n0 + 64 + r0) * K + c0;
  int wo512 = w * 512;
  ld16(sA + wo512, Ap);
  ld16(sB + wo512, Bp0);
  ld16(sB + wo512 + 2048, Bp1);
  int cur = 0;
  for (int kb = 0; kb < K; kb += 32) {
    __syncthreads();
    int nxt = cur ^ 1;
    if (kb + 32 < K) {
      u16* nA = sA + nxt * 2048;
      u16* nB = sB + nxt * 4096;
      ld16(nA + wo512, Ap + kb + 32);
      ld16(nB + wo512, Bp0 + kb + 32);
      ld16(nB + wo512 + 2048, Bp1 + kb + 32);
    }
    const u16* cA = sA + cur * 2048;
    const u16* cB = sB + cur * 4096;
    bf16x8 fa[4], fb[2];
#pragma unroll
    for (int i = 0; i < 4; ++i) fa[i] = *(const bf16x8*)&cA[(i * 16 + li) * 32 + q4 * 8];
#pragma unroll
    for (int j = 0; j < 2; ++j) fb[j] = *(const bf16x8*)&cB[(nw + j * 16 + li) * 32 + q4 * 8];
#pragma unroll
    for (int mt = 0; mt < 4; ++mt)
#pragma unroll
      for (int nt = 0; nt < 2; ++nt) acc[mt][nt] = MFMA(fa[mt], fb[nt], acc[mt][nt]);
    cur = nxt;
  }
#pragma unroll
  for (int mt = 0; mt < 4; ++mt)
#pragma unroll
    for (int r = 0; r < 4; ++r) {
      size_t row = m0 + mt * 16 + q4 * 4 + r;
#pragma unroll
      for (int nt = 0; nt < 2; ++nt) C[row * N + n0 + nw + nt * 16 + li] = acc[mt][nt][r];
    }
}

// ---------------- conv1d k=7 via MFMA; z=0:q, 1:k, 2:v (v written transposed [bn][d][L]) ----------------
// (R8 form — do NOT fuse foreign GEMM work in here; R9 tried and regressed.)
__global__ __launch_bounds__(256) void conv3(const u16* __restrict__ x,
                                             const u16* __restrict__ wTq, const u16* __restrict__ wTk,
                                             const u16* __restrict__ wTv,
                                             const float* __restrict__ cbq, const float* __restrict__ cbk,
                                             const float* __restrict__ cbv,
                                             u16* __restrict__ qh, u16* __restrict__ kh, u16* __restrict__ vtg) {
  __shared__ u16 sX[70 * 72];
  int z = blockIdx.z;
  const u16* wT = z == 0 ? wTq : z == 1 ? wTk : wTv;
  const float* bias = z == 0 ? cbq : z == 1 ? cbk : cbv;
  int t = threadIdx.x;
  int w = t >> 6, lane = t & 63;
  int q4 = lane >> 4, li = lane & 15;
  int l0 = blockIdx.x << 6, bn = blockIdx.y;
  int b = bn >> 4, n = bn & 15;
  const u16* xb = x + b * 3072 + z * 1024 + n * 64;
  for (int e = t; e < 560; e += 256) {
    int ro = e >> 3, c = e & 7;
    int l = l0 - 3 + ro;
    u16x8 v = {0, 0, 0, 0, 0, 0, 0, 0};
    if (l >= 0 && l < L) v = *(const u16x8*)(xb + (size_t)l * 12288 + c * 8);
    *(u16x8*)&sX[ro * 72 + c * 8] = v;
  }
  bf16x8 Bw[7][2];
#pragma unroll
  for (int tt = 0; tt < 7; ++tt)
#pragma unroll
    for (int kc = 0; kc < 2; ++kc)
      Bw[tt][kc] = *(const bf16x8*)(wT + (tt * 64 + w * 16 + li) * 64 + kc * 32 + q4 * 8);
  f32x4 acc[4];
#pragma unroll
  for (int i = 0; i < 4; ++i) acc[i] = (f32x4){0.f, 0.f, 0.f, 0.f};
  __syncthreads();
#pragma unroll
  for (int tt = 0; tt < 7; ++tt)
#pragma unroll
    for (int kc = 0; kc < 2; ++kc)
#pragma unroll
      for (int mt = 0; mt < 4; ++mt) {
        bf16x8 a = *(const bf16x8*)&sX[(mt * 16 + li + tt) * 72 + kc * 32 + q4 * 8];
        acc[mt] = MFMA(a, Bw[tt][kc], acc[mt]);
      }
  float bv = bias[w * 16 + li];
  if (z < 2) {
    u16* out = z == 0 ? qh : kh;
#pragma unroll
    for (int mt = 0; mt < 4; ++mt)
#pragma unroll
      for (int r = 0; r < 4; ++r) {
        int l = l0 + mt * 16 + q4 * 4 + r;
        out[(((size_t)l * 4 + b) * 16 + n) * 64 + w * 16 + li] = f2b(acc[mt][r] + bv);
      }
  } else {
    __syncthreads();
#pragma unroll
    for (int mt = 0; mt < 4; ++mt)
#pragma unroll
      for (int r = 0; r < 4; ++r)
        sX[(w * 16 + li) * 72 + mt * 16 + q4 * 4 + r] = f2b(acc[mt][r] + bv);
    __syncthreads();
    int d = t >> 2, ch = t & 3;
    u16x8 v0 = *(u16x8*)&sX[d * 72 + ch * 16];
    u16x8 v1 = *(u16x8*)&sX[d * 72 + ch * 16 + 8];
    u16* dst = vtg + ((size_t)bn * 64 + d) * 1024 + l0 + ch * 16;
    *(u16x8*)dst = v0;
    *(u16x8*)(dst + 8) = v1;
  }
}

// ---------------- MFMA flash attention with relative shift ----------------
// R6 structure (79us) + R8 fixed-max softmax. 512 blocks, paired q-tiles p/15-p,
// uniform 17 j-tiles, register prefetch (REQUIRED for healthy VGPR allocation).
// R7 un-pairing regressed (110us). DO NOT restructure the pairing.
// R10: sP XOR-swizzle; 1-shfl rel-shift merge; ones-MFMA row-sum (accL);
// setprio around MFMAs. (51.9 -> 46us; VGPR 120, LDS 46080, 3 blocks/CU)
// R12 FAILED (83us): sK/sR dbuf -> LDS 64.5KB -> 2 blocks/CU occupancy cliff.
// R13 FAILED (204us): launch_bounds(256,4) + V-in-reg -> VGPR spills to scratch.
// LOCAL-OPTIMUM BUDGET: LDS 46080, VGPR ~120-124. DO NOT perturb either budget.
// R15: sliding-window sR ring (phys = (l + 64*jt) & 127): jt>=1 stages only the
// 64 NEW rows (pR 4->2). 45.4 -> 44.4us.
// R16: bit-identical VALU trims — SCALEF folded into Aw/Ar (0.125 = 2^-3, pure
// exponent shift: accS/accG scale EXACTLY, Sv unchanged), f2b -> native cast
// (compiler fuses v_cvt_pk_bf16_f32 pairs). No structural change.
__global__ __launch_bounds__(256) void rel_attn(const u16* __restrict__ qh, const u16* __restrict__ kh,
                                                const u16* __restrict__ vt, const u16* __restrict__ rhk,
                                                const float* __restrict__ rwb_, const float* __restrict__ rrb_,
                                                u16* __restrict__ vec) {
  __shared__ u16 sK[64][72];
  __shared__ u16 sVt[64][72];
  __shared__ u16 sR[128][72];
  __shared__ u16 sP[4][16][72];
  int t = threadIdx.x;
  int w = t >> 6, lane = t & 63;
  int q4 = lane >> 4, li = lane & 15;
  int p = blockIdx.x, bn = blockIdx.y;
  int b = bn >> 4, n = bn & 15;
  int base_w = 48 - w * 16;
  const u16* vtb = vt + (size_t)bn * 64 * 1024;
  int er0 = t >> 3, ec = (t & 7) * 8;
  bf16x8 vone;
#pragma unroll
  for (int j = 0; j < 8; ++j) vone[j] = (__bf16)1.0f;
  float rwbv[2][8], rrbv[2][8];
#pragma unroll
  for (int kc = 0; kc < 2; ++kc)
#pragma unroll
    for (int j = 0; j < 8; ++j) {
      int d = kc * 32 + q4 * 8 + j;
      rwbv[kc][j] = rwb_[n * 64 + d];
      rrbv[kc][j] = rrb_[n * 64 + d];
    }
  for (int half = 0; half < 2; ++half) {
    int qt = (half == 0) ? p : 15 - p;
    int i0 = qt << 6;
    bf16x8 Aw[2], Ar[2];
    {
      const u16* qrow = qh + (((size_t)(i0 + w * 16 + li) * 4 + b) * 16 + n) * 64;
#pragma unroll
      for (int kc = 0; kc < 2; ++kc) {
        bf16x8 qv = *(const bf16x8*)(qrow + kc * 32 + q4 * 8);
        bf16x8 aw, ar;
#pragma unroll
        for (int j = 0; j < 8; ++j) {
          float qf = (float)qv[j];
          // SCALEF folded here: 2^-3 scale = exponent-only change, bf16
          // rounding identical -> accS/accG exactly 0.125x, Sv bit-identical.
          aw[j] = (__bf16)((qf + rwbv[kc][j]) * SCALEF);
          ar[j] = (__bf16)((qf + rrbv[kc][j]) * SCALEF);
        }
        Aw[kc] = aw;
        Ar[kc] = ar;
      }
    }
    f32x4 accO[4];
#pragma unroll
    for (int i = 0; i < 4; ++i) accO[i] = (f32x4){0.f, 0.f, 0.f, 0.f};
    f32x4 accL = (f32x4){0.f, 0.f, 0.f, 0.f};  // ones-MFMA row-sum of P
    int ntile = qt + 1;
    u16x8 pK[2], pV[2], pR[4];
    {
      int j0 = 0, gB = 960 - i0;
#pragma unroll
      for (int i = 0; i < 2; ++i) {
        int row = er0 + i * 32;
        pK[i] = *(const u16x8*)(kh + (((size_t)(j0 + row) * 4 + b) * 16 + n) * 64 + ec);
        pV[i] = *(const u16x8*)(vtb + (size_t)row * 1024 + j0 + ec);
      }
#pragma unroll
      for (int i = 0; i < 4; ++i) {
        int m = er0 + i * 32;
        int g = gB + m;
        if (g > L - 1) g = L - 1;
        pR[i] = *(const u16x8*)(rhk + (size_t)g * 1024 + n * 64 + ec);
      }
    }
    for (int jt = 0; jt < ntile; ++jt) {
      int rsh = (jt & 1) << 6;  // R ring phase: phys = (logical + rsh) & 127
      __syncthreads();
#pragma unroll
      for (int i = 0; i < 2; ++i) {
        *(u16x8*)&sK[er0 + i * 32][ec] = pK[i];
        *(u16x8*)&sVt[er0 + i * 32][ec] = pV[i];
      }
      if (jt == 0) {
        // full window restage (start of each half)
#pragma unroll
        for (int i = 0; i < 4; ++i) *(u16x8*)&sR[er0 + i * 32][ec] = pR[i];
      } else {
        // only the 64 NEW rows: logical [64,128) -> phys (er0+i*32) + (rsh^64)
#pragma unroll
        for (int i = 0; i < 2; ++i) *(u16x8*)&sR[(er0 + i * 32) + (rsh ^ 64)][ec] = pR[i];
      }
      __syncthreads();
      if (jt + 1 < ntile) {
        int j0n = (jt + 1) << 6;
#pragma unroll
        for (int i = 0; i < 2; ++i) {
          int row = er0 + i * 32;
          pK[i] = *(const u16x8*)(kh + (((size_t)(j0n + row) * 4 + b) * 16 + n) * 64 + ec);
          pV[i] = *(const u16x8*)(vtb + (size_t)row * 1024 + j0n + ec);
        }
        // prefetch only window jt+1's NEW rows: logical [64,128) -> g = gB(jt+1)+64+x
        int gN = 960 - i0 + j0n + 64;
#pragma unroll
        for (int i = 0; i < 2; ++i) {
          int g = gN + er0 + i * 32;
          if (g > L - 1) g = L - 1;
          pR[i] = *(const u16x8*)(rhk + (size_t)g * 1024 + n * 64 + ec);
        }
      }
      int j0 = jt << 6;
      f32x4 accS[4], accG[5];
#pragma unroll
      for (int i = 0; i < 4; ++i) accS[i] = (f32x4){0.f, 0.f, 0.f, 0.f};
#pragma unroll
      for (int i = 0; i < 5; ++i) accG[i] = (f32x4){0.f, 0.f, 0.f, 0.f};
      __builtin_amdgcn_s_setprio(1);
#pragma unroll
      for (int kc = 0; kc < 2; ++kc) {
#pragma unroll
        for (int nt = 0; nt < 4; ++nt) {
          bf16x8 fk = *(const bf16x8*)&sK[nt * 16 + li][kc * 32 + q4 * 8];
          accS[nt] = MFMA(Aw[kc], fk, accS[nt]);
        }
#pragma unroll
        for (int nt = 0; nt < 5; ++nt) {
          int rrow = (base_w + nt * 16 + li + rsh) & 127;
          bf16x8 fr = *(const bf16x8*)&sR[rrow][kc * 32 + q4 * 8];
          accG[nt] = MFMA(Ar[kc], fr, accG[nt]);
        }
      }
      __builtin_amdgcn_s_setprio(0);
      // rel-shift merge: pre-merge the two candidate G tiles on the SOURCE lane
      // (src/dst share q4 hence il), then a single bpermute moves it.
      float Sv[4][4];
#pragma unroll
      for (int nt = 0; nt < 4; ++nt)
#pragma unroll
        for (int r = 0; r < 4; ++r) {
          int il = q4 * 4 + r;
          int srcc = li + 15 - il;
          int lsrc = (lane & 48) | (srcc & 15);
          float pm = (li >= 15 - il) ? accG[nt][r] : accG[nt + 1][r];
          float g = __shfl(pm, lsrc);
          Sv[nt][r] = accS[nt][r] + g;  // scale pre-folded into Aw/Ar
        }
      if (jt == qt) {
#pragma unroll
        for (int nt = 0; nt < 4; ++nt)
#pragma unroll
          for (int r = 0; r < 4; ++r)
            if (j0 + nt * 16 + li > i0 + w * 16 + q4 * 4 + r) Sv[nt][r] = NEGF;
      }
      // exp + swizzled P store (row = q4*4+r; col bits[3:4] ^= q4 -> conflict-free)
#pragma unroll
      for (int nt = 0; nt < 4; ++nt)
#pragma unroll
        for (int r = 0; r < 4; ++r) {
          float pv = __expf(Sv[nt][r]);
          sP[w][q4 * 4 + r][(nt * 16 + li) ^ (q4 << 3)] = f2b(pv);
        }
      __builtin_amdgcn_s_setprio(1);
#pragma unroll
      for (int kc = 0; kc < 2; ++kc) {
        bf16x8 ap = *(const bf16x8*)&sP[w][li][kc * 32 + ((q4 ^ ((li >> 2) & 3)) << 3)];
        accL = MFMA(ap, vone, accL);  // row-sum of P: replaces the psum butterfly
#pragma unroll
        for (int nt = 0; nt < 4; ++nt) {
          bf16x8 fv = *(const bf16x8*)&sVt[nt * 16 + li][kc * 32 + q4 * 8];
          accO[nt] = MFMA(ap, fv, accO[nt]);
        }
      }
      __builtin_amdgcn_s_setprio(0);
    }
#pragma unroll
    for (int r = 0; r < 4; ++r) {
      int il = q4 * 4 + r;
      int ig = i0 + w * 16 + il;
      float inv = 1.0f / accL[r];
      u16* orow = vec + (((size_t)ig * 4 + b) * 16 + n) * 64;
#pragma unroll
      for (int nt = 0; nt < 4; ++nt) orow[nt * 16 + li] = f2b(accO[nt][r] * inv);
    }
  }
}

// ---------------- residual + layernorm ----------------
__global__ __launch_bounds__(256) void resid_ln(const float* __restrict__ w,
                                                const float* __restrict__ attn,
                                                const float* __restrict__ gamma,
                                                const float* __restrict__ beta,
                                                float* __restrict__ out) {
  __shared__ float ssum[4], ssq[4];
  int row = blockIdx.x, t = threadIdx.x;
  float4 xw = *(const float4*)&w[(size_t)row * 1024 + t * 4];
  float4 xa = *(const float4*)&attn[(size_t)row * 1024 + t * 4];
  float4 x = make_float4(xw.x + xa.x, xw.y + xa.y, xw.z + xa.z, xw.w + xa.w);
  float s = x.x + x.y + x.z + x.w;
  float sq = x.x * x.x + x.y * x.y + x.z * x.z + x.w * x.w;
#pragma unroll
  for (int off = 32; off > 0; off >>= 1) {
    s += __shfl_down(s, off);
    sq += __shfl_down(sq, off);
  }
  int wid = t >> 6;
  if ((t & 63) == 0) { ssum[wid] = s; ssq[wid] = sq; }
  __syncthreads();
  s = ssum[0] + ssum[1] + ssum[2] + ssum[3];
  sq = ssq[0] + ssq[1] + ssq[2] + ssq[3];
  float mean = s * (1.0f / 1024.0f);
  float var = sq * (1.0f / 1024.0f) - mean * mean;
  float rstd = rsqrtf(var + 1e-5f);
  float4 g = *(const float4*)&gamma[t * 4];
  float4 bb = *(const float4*)&beta[t * 4];
  float4 o;
  o.x = (x.x - mean) * rstd * g.x + bb.x;
  o.y = (x.y - mean) * rstd * g.y + bb.y;
  o.z = (x.z - mean) * rstd * g.z + bb.z;
  o.w = (x.w - mean) * rstd * g.w + bb.w;
  *(float4*)&out[(size_t)row * 1024 + t * 4] = o;
}

extern "C" void kernel_launch(void* const* d_in, const int* in_sizes, int n_in,
                              void* d_out, int out_size, void* d_ws, size_t ws_size,
                              hipStream_t stream) {
  const float* w     = (const float*)d_in[0];
  const float* r     = (const float*)d_in[1];
  const float* rwb   = (const float*)d_in[2];
  const float* rrb   = (const float*)d_in[3];
  const float* W_qkv = (const float*)d_in[4];
  const float* W_r   = (const float*)d_in[5];
  const float* W_o   = (const float*)d_in[6];
  const float* cwq   = (const float*)d_in[7];
  const float* cbq   = (const float*)d_in[8];
  const float* cwk   = (const float*)d_in[9];
  const float* cbk   = (const float*)d_in[10];
  const float* cwv   = (const float*)d_in[11];
  const float* cbv   = (const float*)d_in[12];
  const float* gamma = (const float*)d_in[13];
  const float* beta  = (const float*)d_in[14];
  float* outp = (float*)d_out;

  char* wsb = (char*)d_ws;
  u16*   heads   = (u16*)(wsb);                 // [4096][3072] bf16 = 24 MB
  u16*   vec     = (u16*)(wsb);                 // alias (heads dead after convs): 8 MB
  float* attnf   = (float*)(wsb + 8388608);     // 16 MB (within dead heads region)
  u16*   qh      = (u16*)(wsb + 25165824);      // 8 MB
  u16*   kh      = (u16*)(wsb + 33554432);      // 8 MB
  u16*   rhk     = (u16*)(wsb + 50331648);      // 2 MB
  u16*   w_bf    = (u16*)(wsb + 52428800);
  u16*   wqkv_bf = (u16*)(wsb + 60817408);
  u16*   r_bf    = (u16*)(wsb + 67108864);
  u16*   wr_bf   = (u16*)(wsb + 69206016);
  u16*   wo_bf   = (u16*)(wsb + 71303168);
  u16*   wTq     = (u16*)(wsb + 73400320);
  u16*   wTk     = (u16*)(wsb + 73457664);
  u16*   wTv     = (u16*)(wsb + 73515008);
  u16*   vt      = (u16*)(wsb + 73572352);      // [64][64][1024] bf16 = 8 MB

  dim3 blk(256);
  prep<<<10576, blk, 0, stream>>>(w, W_qkv, r, W_r, W_o, cwq, cwk, cwv,
                                  w_bf, wqkv_bf, r_bf, wr_bf, wo_bf, wTq, wTk, wTv);
  gemm_stage1<<<208, dim3(512), 0, stream>>>(w_bf, wqkv_bf, heads, r_bf, wr_bf, rhk);
  conv3<<<dim3(16, 64, 3), blk, 0, stream>>>(heads, wTq, wTk, wTv, cbq, cbk, cbv, qh, kh, vt);
  rel_attn<<<dim3(8, 64), blk, 0, stream>>>(qh, kh, vt, rhk, rwb, rrb, vec);
  gemm_wo<<<dim3(8, 64), blk, 0, stream>>>(vec, wo_bf, attnf);
  resid_ln<<<4096, blk, 0, stream>>>(w, attnf, gamma, beta, outp);
}